// Round 13
// baseline (254.451 us; speedup 1.0000x reference)
//
#include <hip/hip_runtime.h>
#include <stdint.h>

typedef short s16x8 __attribute__((ext_vector_type(8)));
typedef unsigned short u16x8 __attribute__((ext_vector_type(8)));
typedef unsigned short u16x4 __attribute__((ext_vector_type(4)));
typedef float f32x4 __attribute__((ext_vector_type(4)));

__device__ __forceinline__ float bf2f(unsigned short u) {
  union { unsigned u; float f; } c; c.u = ((unsigned)u) << 16; return c.f;
}
__device__ __forceinline__ unsigned short f2bf(float f) {
  union { float f; unsigned u; } c; c.f = f;
  unsigned u = c.u + 0x7fffu + ((c.u >> 16) & 1u);
  return (unsigned short)(u >> 16);
}

// async global->LDS, 16B per lane; lds base must be wave-uniform (HW adds lane*16)
__device__ __forceinline__ void g2l16(const void* g, void* l) {
  __builtin_amdgcn_global_load_lds(
      (const __attribute__((address_space(1))) void*)(unsigned long long)g,
      (__attribute__((address_space(3))) void*)(unsigned)(unsigned long long)l,
      16, 0, 0);
}

// C[M,N] = scale*(A[M,K] @ Bt[N,K]^T)(+bias). A,Bt bf16 K-contiguous.
// MT x 128 tile; MT=128: 4 waves / MT=256: 8 waves; wave tile always 64x64
// (4x4 16x16x32 MFMA). LDS staging XOR-swizzled (chunk c of row r at slot
// c^(r&7)): conflict-free [R6: SQ_LDS_BANK_CONFLICT=0].
// YB: XCD-locality remap (blocks sharing a B-tile sit 8 apart).
// MODE 1: bf16 out, optional per-col bias (bias[N]), LDS-bounce vector store.
// MODE 2: bf16 out = exp(scale*acc), row sums atomically added to rowsum[bz*M+row].
// MODE 3: qkvo fused: bx<8 -> MODE-1 store to C (qkT, ldc); bx>=8 ->
//         TRANSPOSED store to C2 (vo[d][n], ldc2) via d-major LDS bounce,
//         replacing the separate transpose_bf kernel [R13].
// grid.z = batches*nsplit; ks=z%nsplit selects K-chunk, out += ks*sSplit.
// smem must cover staging ((MT+128)*64), bounce (128*136), vo-bounce (64*264).
template <int MODE, int MT, int YB>
__global__ __launch_bounds__(2 * MT) void gemm_abt(
    const unsigned short* __restrict__ A, int lda,
    const unsigned short* __restrict__ Bt, int ldb,
    unsigned short* __restrict__ C, int ldc,
    const float* __restrict__ bias,
    float* __restrict__ rowsum,
    int M, int N, int K, int nsplit,
    long long sA, long long sBt, long long sC, long long sSplit,
    float scale,
    unsigned short* __restrict__ C2, int ldc2, long long sC2)
{
  constexpr int STAGE_ELEMS  = (MT + 128) * 64;
  constexpr int BOUNCE_ELEMS = 128 * 136;
  constexpr int SMEM_ELEMS = STAGE_ELEMS > BOUNCE_ELEMS ? STAGE_ELEMS : BOUNCE_ELEMS;
  __shared__ __align__(16) unsigned short smem[SMEM_ELEMS];
  unsigned short* As = smem;
  unsigned short* Bs = smem + MT * 64;

  const int ks = blockIdx.z % nsplit;
  const int bz = blockIdx.z / nsplit;
  A  += (long long)bz * sA;
  Bt += (long long)bz * sBt;
  C  += (long long)bz * sC + (long long)ks * sSplit;

  int bx, by;
  if (YB > 0) {
    const int lin = blockIdx.x + (int)gridDim.x * blockIdx.y;
    bx = (lin & 7) | ((lin >> (3 + YB)) << 3);
    by = (lin >> 3) & ((1 << YB) - 1);
  } else {
    bx = blockIdx.x;
    by = blockIdx.y;
  }

  const int tile_m = by * MT;
  const int tile_n = bx * 128;

  const int tid  = threadIdx.x;
  const int wid  = tid >> 6;
  const int lane = tid & 63;
  const int wm = (wid >> 1) * 64;   // wave's 64-row strip (2 or 4 strips)
  const int wn = (wid & 1) * 64;    // wave's 64-col strip
  const int lr = lane & 15;         // fragment row (m for A, n for B)
  const int lq = lane >> 4;         // quad -> k offset lq*8

  const int srow = lane >> 3;                         // row within 8-row chunk
  const int scol = ((lane & 7) ^ (srow & 7)) * 8;     // XOR-swizzled col chunk

  f32x4 acc[4][4];
  const f32x4 zero4 = {0.f, 0.f, 0.f, 0.f};
  #pragma unroll
  for (int i = 0; i < 4; ++i)
    #pragma unroll
    for (int j = 0; j < 4; ++j) acc[i][j] = zero4;

  const unsigned short* Arow = A  + (long long)tile_m * lda;
  const unsigned short* Brow = Bt + (long long)tile_n * ldb;

  const int kLen = K / nsplit;
  const int kBeg = ks * kLen;

  constexpr int ACH   = MT / 8;          // A chunks (8 rows x 64 cols = 1KB)
  constexpr int NCH   = ACH + 16;        // + 16 B chunks
  constexpr int NW    = MT / 32;         // waves
  constexpr int PERW  = NCH / NW;        // chunks per wave (8 or 6)

  for (int k0 = kBeg; k0 < kBeg + kLen; k0 += 64) {
    #pragma unroll
    for (int c = 0; c < PERW; ++c) {
      const int chunk = wid * PERW + c;  // wave-uniform
      if (chunk < ACH) {
        const int row = chunk * 8 + srow;
        g2l16(Arow + (long long)row * lda + k0 + scol, smem + chunk * 512);
      } else {
        const int row = (chunk - ACH) * 8 + srow;
        g2l16(Brow + (long long)row * ldb + k0 + scol, smem + chunk * 512);
      }
    }
    __syncthreads();
    #pragma unroll
    for (int kss = 0; kss < 2; ++kss) {
      const int cch = kss * 4 + lq;                 // 16B-chunk index in row
      s16x8 af[4], bfr[4];
      #pragma unroll
      for (int i = 0; i < 4; ++i) {
        const int row = wm + i * 16 + lr;
        af[i] = *(const s16x8*)&As[row * 64 + ((cch ^ (row & 7)) * 8)];
      }
      #pragma unroll
      for (int j = 0; j < 4; ++j) {
        const int row = wn + j * 16 + lr;
        bfr[j] = *(const s16x8*)&Bs[row * 64 + ((cch ^ (row & 7)) * 8)];
      }
      #pragma unroll
      for (int i = 0; i < 4; ++i)
        #pragma unroll
        for (int j = 0; j < 4; ++j)
          acc[i][j] = __builtin_amdgcn_mfma_f32_16x16x32_bf16(af[i], bfr[j], acc[i][j], 0, 0, 0);
    }
    __syncthreads();
  }

  // ---- epilogue. C/D layout col=lane&15, row=(lane>>4)*4+reg [m89-verified]

  if (MODE == 3 && bx >= 8) {
    // transposed store: tile is 256 n (rows) x 128 d (cols) -> vo[d][n].
    // pass p handles d-half p*64: waves with wn==p*64 write d-major bounce
    // (ld=264: dl*264 multiple of 4 -> aligned u16x4 writes, 2-way banks),
    // then all 512 threads store 64 d-rows x 256 n coalesced.
    const int tile_d0 = (bx - 8) * 128;
    unsigned short* V = C2 + (long long)bz * sC2;
    #pragma unroll
    for (int p = 0; p < 2; ++p) {
      if ((wid & 1) == p) {
        #pragma unroll
        for (int j = 0; j < 4; ++j) {
          const int dl = j * 16 + lr;            // 0..63 within pass
          #pragma unroll
          for (int i = 0; i < 4; ++i) {
            const int nbase = wm + i * 16 + lq * 4;
            u16x4 w4;
            #pragma unroll
            for (int r = 0; r < 4; ++r) w4[r] = f2bf(acc[i][j][r]);
            *(u16x4*)&smem[dl * 264 + nbase] = w4;
          }
        }
      }
      __syncthreads();
      {
        const int dl = tid >> 3;
        const int nb = (tid & 7) * 32;
        unsigned short* dst = V + (long long)(tile_d0 + p * 64 + dl) * ldc2 + tile_m + nb;
        #pragma unroll
        for (int k = 0; k < 4; ++k) {
          u16x8 v = *(const u16x8*)&smem[dl * 264 + nb + k * 8];
          *(u16x8*)&dst[k * 8] = v;
        }
      }
      if (p == 0) __syncthreads();
    }
    return;
  }

  // MODE 2: exp-transform acc in regs + rowsum atomics (no LDS dependency)
  if (MODE == 2) {
    #pragma unroll
    for (int i = 0; i < 4; ++i) {
      float rs[4] = {0.f, 0.f, 0.f, 0.f};
      #pragma unroll
      for (int j = 0; j < 4; ++j)
        #pragma unroll
        for (int r = 0; r < 4; ++r) {
          acc[i][j][r] = __expf(acc[i][j][r] * scale);
          rs[r] += acc[i][j][r];
        }
      #pragma unroll
      for (int r = 0; r < 4; ++r) {
        float s = rs[r];
        s += __shfl_xor(s, 1); s += __shfl_xor(s, 2);
        s += __shfl_xor(s, 4); s += __shfl_xor(s, 8);
        if (lr == 0)
          atomicAdd(&rowsum[(long long)bz * M + tile_m + wm + i * 16 + lq * 4 + r], s);
      }
    }
  }

  // bounce passes: 128 rows at a time through smem (ld=136)
  if (MT == 128) {
    #pragma unroll
    for (int i = 0; i < 4; ++i) {
      const int lrow0 = wm + i * 16 + lq * 4;
      #pragma unroll
      for (int j = 0; j < 4; ++j) {
        const int lcol = wn + j * 16 + lr;
        const float bcol = ((MODE == 1 || MODE == 3) && bias) ? bias[tile_n + lcol] : 0.f;
        #pragma unroll
        for (int r = 0; r < 4; ++r) {
          const float v = (MODE == 2) ? acc[i][j][r] : acc[i][j][r] * scale + bcol;
          smem[(lrow0 + r) * 136 + lcol] = f2bf(v);
        }
      }
    }
    __syncthreads();
    const int row = tid >> 1;
    const int cb = (tid & 1) * 64;
    #pragma unroll
    for (int k = 0; k < 8; ++k) {
      u16x8 v = *(const u16x8*)&smem[row * 136 + cb + k * 8];
      *(u16x8*)&C[(long long)(tile_m + row) * ldc + tile_n + cb + k * 8] = v;
    }
  } else {
    #pragma unroll
    for (int p = 0; p < 2; ++p) {
      if ((wm >> 7) == p) {
        const int lwm = wm & 127;
        #pragma unroll
        for (int i = 0; i < 4; ++i) {
          const int lrow0 = lwm + i * 16 + lq * 4;
          #pragma unroll
          for (int j = 0; j < 4; ++j) {
            const int lcol = wn + j * 16 + lr;
            const float bcol = ((MODE == 1 || MODE == 3) && bias) ? bias[tile_n + lcol] : 0.f;
            #pragma unroll
            for (int r = 0; r < 4; ++r) {
              const float v = (MODE == 2) ? acc[i][j][r] : acc[i][j][r] * scale + bcol;
              smem[(lrow0 + r) * 136 + lcol] = f2bf(v);
            }
          }
        }
      }
      __syncthreads();
      if ((tid >> 8) == p) {
        const int t2 = tid & 255;
        const int row = t2 >> 1;
        const int cb = (t2 & 1) * 64;
        #pragma unroll
        for (int k = 0; k < 8; ++k) {
          u16x8 v = *(const u16x8*)&smem[row * 136 + cb + k * 8];
          *(u16x8*)&C[(long long)(tile_m + p * 128 + row) * ldc + tile_n + cb + k * 8] = v;
        }
      }
      if (p == 0) __syncthreads();
    }
  }
}

// prep: merged weight-convert + bias_pp + x transpose [R13, -2 dispatches].
// blocks 0..1023:    wq,wk -> W3 rows 0..1023; wv -> wvT_b TRANSPOSED;
//                    wo -> wo_b; bqk=[bq|bk]; zero rowsum[8192].
// blocks 1024..1151: bpp[d] = sum_c wo[d,c]*bv[c] + bo[d] (one wave per d).
// blocks 1152+:      x fp32 [C][N] -> xT bf16 [N][C] (32x32 tiles).
__global__ __launch_bounds__(256) void prep(
    const float* __restrict__ x,
    const float* __restrict__ wq, const float* __restrict__ wk,
    const float* __restrict__ wv, const float* __restrict__ wo,
    const float* __restrict__ bq, const float* __restrict__ bk,
    const float* __restrict__ bv, const float* __restrict__ bo,
    unsigned short* __restrict__ W3, unsigned short* __restrict__ wvT_b,
    unsigned short* __restrict__ wo_b, unsigned short* __restrict__ xT,
    float* __restrict__ bqk, float* __restrict__ bpp,
    float* __restrict__ rowsum)
{
  __shared__ float tile[32][33];
  const int lin = blockIdx.x;
  const int tid = threadIdx.x;
  if (lin < 1024) {
    const int i = lin * 256 + tid;
    W3[i]          = f2bf(wq[i]);
    W3[262144 + i] = f2bf(wk[i]);
    wvT_b[i]       = f2bf(wv[(i & 511) * 512 + (i >> 9)]);  // wvT[c,t]=wv[t,c]
    wo_b[i]        = f2bf(wo[i]);
    if (i < 512) { bqk[i] = bq[i]; bqk[512 + i] = bk[i]; }
    if (i < 8192) rowsum[i] = 0.f;
  } else if (lin < 1152) {
    const int w = tid >> 6, lane = tid & 63;
    const int d = (lin - 1024) * 4 + w;
    const float* row = wo + (long long)d * 512;
    float s = 0.f;
    #pragma unroll
    for (int c = 0; c < 512; c += 64) s += row[c + lane] * bv[c + lane];
    #pragma unroll
    for (int o = 32; o > 0; o >>= 1) s += __shfl_xor(s, o, 64);
    if (lane == 0) bpp[d] = s + bo[d];
  } else {
    const int t = lin - 1152;
    const int n0 = (t & 127) * 32;
    const int c0 = ((t >> 7) & 15) * 32;
    const int bz = t >> 11;
    const int tx = tid & 31, ty = tid >> 5;
    const long long boff = (long long)bz * (512LL * 4096);
    #pragma unroll
    for (int k = 0; k < 32; k += 8)
      tile[ty + k][tx] = x[boff + (long long)(c0 + ty + k) * 4096 + n0 + tx];
    __syncthreads();
    #pragma unroll
    for (int k = 0; k < 32; k += 8)
      xT[boff + (long long)(n0 + ty + k) * 512 + c0 + tx] = f2bf(tile[tx][ty + k]);
  }
}

// out[b][d][n] = (sum of 4 bf16 partial streams)[b][d][n] / rowsum[b][n] + bpp[d]
// i = ((b*512 + d)*4096 + n); 8 contiguous n per thread; fp32 out
__global__ __launch_bounds__(256) void reduce4_norm_out(
    const unsigned short* __restrict__ p, long long L,
    const float* __restrict__ rowsum, const float* __restrict__ bpp,
    float* __restrict__ o)
{
  const long long i = 8LL * (blockIdx.x * 256 + threadIdx.x);
  const int b = (int)(i >> 21);
  const int d = (int)((i >> 12) & 511);
  const int n = (int)(i & 4095);
  const float bb = bpp[d];
  const float* rs = &rowsum[b * 4096 + n];
  u16x8 a  = *(const u16x8*)&p[i];
  u16x8 b1 = *(const u16x8*)&p[L + i];
  u16x8 c  = *(const u16x8*)&p[2 * L + i];
  u16x8 d1 = *(const u16x8*)&p[3 * L + i];
  f32x4 o0, o1;
  #pragma unroll
  for (int j = 0; j < 4; ++j) {
    o0[j] = ((bf2f(a[j]) + bf2f(b1[j])) + (bf2f(c[j]) + bf2f(d1[j]))) / rs[j] + bb;
    o1[j] = ((bf2f(a[4 + j]) + bf2f(b1[4 + j])) + (bf2f(c[4 + j]) + bf2f(d1[4 + j]))) / rs[4 + j] + bb;
  }
  *(f32x4*)&o[i] = o0;
  *(f32x4*)&o[i + 4] = o1;
}

extern "C" void kernel_launch(void* const* d_in, const int* in_sizes, int n_in,
                              void* d_out, int out_size, void* d_ws, size_t ws_size,
                              hipStream_t stream) {
  (void)in_sizes; (void)n_in; (void)out_size; (void)ws_size;
  const float* x  = (const float*)d_in[0];
  const float* wq = (const float*)d_in[1];
  const float* bq = (const float*)d_in[2];
  const float* wk = (const float*)d_in[3];
  const float* bk = (const float*)d_in[4];
  const float* wv = (const float*)d_in[5];
  const float* bv = (const float*)d_in[6];
  const float* wo = (const float*)d_in[7];
  const float* bo = (const float*)d_in[8];
  float* out = (float*)d_out;

  const int Cc = 512, N = 4096, Bn = 2;
  const int CC = Cc * Cc;                    // 262,144
  const long long NC  = (long long)N * Cc;   // 2,097,152
  const long long NK  = (long long)N * 1024; // 4,194,304 (q|k rows)
  const long long NN  = (long long)N * N;    // 16,777,216

  char* wsb = (char*)d_ws;
  unsigned short* W3    = (unsigned short*)wsb;               // [1536][512] Wq|Wk|Wp
  unsigned short* wvT_b = W3 + 3LL * CC;                      // [512][512] wv^T
  unsigned short* wo_b  = wvT_b + CC;                         // [512][512]
  float*          bqk   = (float*)(wo_b + CC);                // [1024]
  float*          bpp   = bqk + 1024;                         // [512]  wo*bv+bo
  float*          rsum  = bpp + 512;                          // [8192]
  unsigned short* xT    = (unsigned short*)(rsum + 8192);     // [B][N][512]
  unsigned short* qkT   = xT + Bn * NC;                       // [B][N][1024] q|k
  unsigned short* vo    = qkT + Bn * NK;                      // [B][512][N]
  unsigned short* S     = vo + Bn * NC;                       // [B][N][N] P_unnorm
  unsigned short* part  = S + Bn * NN;                        // [4][B][512][N] bf16

  const float inv_sqrt_c = 0.044194173824159216f;  // 1/sqrt(512)

  // D1: weights->bf16 (+wv^T), bqk, bpp, rowsum=0, x->xT   (merged)
  prep<<<dim3(1152 + 128 * 16 * Bn), 256, 0, stream>>>(
      x, wq, wk, wv, wo, bq, bk, bv, bo, W3, wvT_b, wo_b, xT, bqk, bpp, rsum);
  // D2: W3 rows 1024+: Wp[d,c] = sum_t wo[d,t] wv[t,c]
  gemm_abt<1, 128, 0><<<dim3(4, 4, 1), 256, 0, stream>>>(
      wo_b, 512, wvT_b, 512, W3 + 2LL * CC, 512, nullptr, nullptr,
      512, 512, 512, 1, 0, 0, 0, 0, 1.0f, nullptr, 0, 0);
  // D3: fused projections: d<1024 -> qkT[n,d]+bias; d>=1024 -> vo[d-1024][n]
  //     (transposed epilogue store; transpose_bf eliminated)
  gemm_abt<3, 256, 0><<<dim3(12, N / 256, Bn), 512, 0, stream>>>(
      xT, Cc, W3, Cc, qkT, 1024, bqk, nullptr, N, 1536, Cc, 1,
      NC, 0, NK, 0, 1.0f, vo, N, NC);
  // D4: P_unnorm[n,m] = exp((1/sqrt(C)) sum_c q[n,c] k[m,c]); rsum += row sums
  gemm_abt<2, 256, 4><<<dim3(N / 128, N / 256, Bn), 512, 0, stream>>>(
      qkT, 1024, qkT + 512, 1024, S, N, nullptr, rsum, N, N, Cc, 1,
      NK, NK, NN, 0, inv_sqrt_c, nullptr, 0, 0);
  // D5: part[ks][b][d][n] = sum_{m in split ks} vo[d,m] P_unnorm[n,m]
  gemm_abt<1, 256, 1><<<dim3(N / 128, 512 / 256, Bn * 4), 512, 0, stream>>>(
      vo, N, S, N, part, N, nullptr, nullptr, 512, N, N, 4,
      NC, NN, NC, (long long)Bn * NC, 1.0f, nullptr, 0, 0);
  // D6: out = (sum of partials)/l[n] + bpp[d]   (fp32, [B][C][H][W])
  reduce4_norm_out<<<dim3((int)((Bn * NC) / 2048)), 256, 0, stream>>>(
      part, (long long)Bn * NC, rsum, bpp, out);
}

// Round 14
// 248.774 us; speedup vs baseline: 1.0228x; 1.0228x over previous
//
#include <hip/hip_runtime.h>
#include <stdint.h>

typedef short s16x8 __attribute__((ext_vector_type(8)));
typedef unsigned short u16x8 __attribute__((ext_vector_type(8)));
typedef unsigned short u16x4 __attribute__((ext_vector_type(4)));
typedef float f32x4 __attribute__((ext_vector_type(4)));

__device__ __forceinline__ float bf2f(unsigned short u) {
  union { unsigned u; float f; } c; c.u = ((unsigned)u) << 16; return c.f;
}
__device__ __forceinline__ unsigned short f2bf(float f) {
  union { float f; unsigned u; } c; c.f = f;
  unsigned u = c.u + 0x7fffu + ((c.u >> 16) & 1u);
  return (unsigned short)(u >> 16);
}

// async global->LDS, 16B per lane; lds base must be wave-uniform (HW adds lane*16)
__device__ __forceinline__ void g2l16(const void* g, void* l) {
  __builtin_amdgcn_global_load_lds(
      (const __attribute__((address_space(1))) void*)(unsigned long long)g,
      (__attribute__((address_space(3))) void*)(unsigned)(unsigned long long)l,
      16, 0, 0);
}

// C[M,N] = scale*(A[M,K] @ Bt[N,K]^T)(+bias). A,Bt bf16 K-contiguous.
// MT x 128 tile; MT=128: 4 waves / MT=256: 8 waves; wave tile always 64x64
// (4x4 16x16x32 MFMA). LDS staging XOR-swizzled (chunk c of row r at slot
// c^(r&7)): conflict-free [R6: SQ_LDS_BANK_CONFLICT=0].
// YB: XCD-locality remap (blocks sharing a B-tile sit 8 apart).
// STRIDE RULE [R13 post-mortem]: input leading dims must NOT be powers of 2 —
// ld=1024 (2048B) cost scores +14% (68->77.7us, same FETCH) vs ld=1536 via
// HBM-bank/L2-set aliasing of the 128 staged rows. Callers pad (1088/4224).
// MODE 1: bf16 out, optional per-col bias (bias[N]), LDS-bounce vector store.
// MODE 2: bf16 out = exp(scale*acc), row sums atomically added to rowsum[bz*M+row].
// MODE 3: qkvo fused: bx<8 -> MODE-1 store to C (qkT, ldc); bx>=8 ->
//         TRANSPOSED store to C2 (vo[d][n], ldc2) via d-major LDS bounce.
// grid.z = batches*nsplit; ks=z%nsplit selects K-chunk, out += ks*sSplit.
// smem must cover staging ((MT+128)*64), bounce (128*136), vo-bounce (64*264).
template <int MODE, int MT, int YB>
__global__ __launch_bounds__(2 * MT) void gemm_abt(
    const unsigned short* __restrict__ A, int lda,
    const unsigned short* __restrict__ Bt, int ldb,
    unsigned short* __restrict__ C, int ldc,
    const float* __restrict__ bias,
    float* __restrict__ rowsum,
    int M, int N, int K, int nsplit,
    long long sA, long long sBt, long long sC, long long sSplit,
    float scale,
    unsigned short* __restrict__ C2, int ldc2, long long sC2)
{
  constexpr int STAGE_ELEMS  = (MT + 128) * 64;
  constexpr int BOUNCE_ELEMS = 128 * 136;
  constexpr int SMEM_ELEMS = STAGE_ELEMS > BOUNCE_ELEMS ? STAGE_ELEMS : BOUNCE_ELEMS;
  __shared__ __align__(16) unsigned short smem[SMEM_ELEMS];
  unsigned short* As = smem;
  unsigned short* Bs = smem + MT * 64;

  const int ks = blockIdx.z % nsplit;
  const int bz = blockIdx.z / nsplit;
  A  += (long long)bz * sA;
  Bt += (long long)bz * sBt;
  C  += (long long)bz * sC + (long long)ks * sSplit;

  int bx, by;
  if (YB > 0) {
    const int lin = blockIdx.x + (int)gridDim.x * blockIdx.y;
    bx = (lin & 7) | ((lin >> (3 + YB)) << 3);
    by = (lin >> 3) & ((1 << YB) - 1);
  } else {
    bx = blockIdx.x;
    by = blockIdx.y;
  }

  const int tile_m = by * MT;
  const int tile_n = bx * 128;

  const int tid  = threadIdx.x;
  const int wid  = tid >> 6;
  const int lane = tid & 63;
  const int wm = (wid >> 1) * 64;   // wave's 64-row strip (2 or 4 strips)
  const int wn = (wid & 1) * 64;    // wave's 64-col strip
  const int lr = lane & 15;         // fragment row (m for A, n for B)
  const int lq = lane >> 4;         // quad -> k offset lq*8

  const int srow = lane >> 3;                         // row within 8-row chunk
  const int scol = ((lane & 7) ^ (srow & 7)) * 8;     // XOR-swizzled col chunk

  f32x4 acc[4][4];
  const f32x4 zero4 = {0.f, 0.f, 0.f, 0.f};
  #pragma unroll
  for (int i = 0; i < 4; ++i)
    #pragma unroll
    for (int j = 0; j < 4; ++j) acc[i][j] = zero4;

  const unsigned short* Arow = A  + (long long)tile_m * lda;
  const unsigned short* Brow = Bt + (long long)tile_n * ldb;

  const int kLen = K / nsplit;
  const int kBeg = ks * kLen;

  constexpr int ACH   = MT / 8;          // A chunks (8 rows x 64 cols = 1KB)
  constexpr int NCH   = ACH + 16;        // + 16 B chunks
  constexpr int NW    = MT / 32;         // waves
  constexpr int PERW  = NCH / NW;        // chunks per wave (8 or 6)

  for (int k0 = kBeg; k0 < kBeg + kLen; k0 += 64) {
    #pragma unroll
    for (int c = 0; c < PERW; ++c) {
      const int chunk = wid * PERW + c;  // wave-uniform
      if (chunk < ACH) {
        const int row = chunk * 8 + srow;
        g2l16(Arow + (long long)row * lda + k0 + scol, smem + chunk * 512);
      } else {
        const int row = (chunk - ACH) * 8 + srow;
        g2l16(Brow + (long long)row * ldb + k0 + scol, smem + chunk * 512);
      }
    }
    __syncthreads();
    #pragma unroll
    for (int kss = 0; kss < 2; ++kss) {
      const int cch = kss * 4 + lq;                 // 16B-chunk index in row
      s16x8 af[4], bfr[4];
      #pragma unroll
      for (int i = 0; i < 4; ++i) {
        const int row = wm + i * 16 + lr;
        af[i] = *(const s16x8*)&As[row * 64 + ((cch ^ (row & 7)) * 8)];
      }
      #pragma unroll
      for (int j = 0; j < 4; ++j) {
        const int row = wn + j * 16 + lr;
        bfr[j] = *(const s16x8*)&Bs[row * 64 + ((cch ^ (row & 7)) * 8)];
      }
      #pragma unroll
      for (int i = 0; i < 4; ++i)
        #pragma unroll
        for (int j = 0; j < 4; ++j)
          acc[i][j] = __builtin_amdgcn_mfma_f32_16x16x32_bf16(af[i], bfr[j], acc[i][j], 0, 0, 0);
    }
    __syncthreads();
  }

  // ---- epilogue. C/D layout col=lane&15, row=(lane>>4)*4+reg [m89-verified]

  if (MODE == 3 && bx >= 8) {
    // transposed store: tile is 256 n (rows) x 128 d (cols) -> vo[d][n].
    const int tile_d0 = (bx - 8) * 128;
    unsigned short* V = C2 + (long long)bz * sC2;
    #pragma unroll
    for (int p = 0; p < 2; ++p) {
      if ((wid & 1) == p) {
        #pragma unroll
        for (int j = 0; j < 4; ++j) {
          const int dl = j * 16 + lr;            // 0..63 within pass
          #pragma unroll
          for (int i = 0; i < 4; ++i) {
            const int nbase = wm + i * 16 + lq * 4;
            u16x4 w4;
            #pragma unroll
            for (int r = 0; r < 4; ++r) w4[r] = f2bf(acc[i][j][r]);
            *(u16x4*)&smem[dl * 264 + nbase] = w4;
          }
        }
      }
      __syncthreads();
      {
        const int dl = tid >> 3;
        const int nb = (tid & 7) * 32;
        unsigned short* dst = V + (long long)(tile_d0 + p * 64 + dl) * ldc2 + tile_m + nb;
        #pragma unroll
        for (int k = 0; k < 4; ++k) {
          u16x8 v = *(const u16x8*)&smem[dl * 264 + nb + k * 8];
          *(u16x8*)&dst[k * 8] = v;
        }
      }
      if (p == 0) __syncthreads();
    }
    return;
  }

  // MODE 2: exp-transform acc in regs + rowsum atomics (no LDS dependency)
  if (MODE == 2) {
    #pragma unroll
    for (int i = 0; i < 4; ++i) {
      float rs[4] = {0.f, 0.f, 0.f, 0.f};
      #pragma unroll
      for (int j = 0; j < 4; ++j)
        #pragma unroll
        for (int r = 0; r < 4; ++r) {
          acc[i][j][r] = __expf(acc[i][j][r] * scale);
          rs[r] += acc[i][j][r];
        }
      #pragma unroll
      for (int r = 0; r < 4; ++r) {
        float s = rs[r];
        s += __shfl_xor(s, 1); s += __shfl_xor(s, 2);
        s += __shfl_xor(s, 4); s += __shfl_xor(s, 8);
        if (lr == 0)
          atomicAdd(&rowsum[(long long)bz * M + tile_m + wm + i * 16 + lq * 4 + r], s);
      }
    }
  }

  // bounce passes: 128 rows at a time through smem (ld=136)
  if (MT == 128) {
    #pragma unroll
    for (int i = 0; i < 4; ++i) {
      const int lrow0 = wm + i * 16 + lq * 4;
      #pragma unroll
      for (int j = 0; j < 4; ++j) {
        const int lcol = wn + j * 16 + lr;
        const float bcol = ((MODE == 1 || MODE == 3) && bias) ? bias[tile_n + lcol] : 0.f;
        #pragma unroll
        for (int r = 0; r < 4; ++r) {
          const float v = (MODE == 2) ? acc[i][j][r] : acc[i][j][r] * scale + bcol;
          smem[(lrow0 + r) * 136 + lcol] = f2bf(v);
        }
      }
    }
    __syncthreads();
    const int row = tid >> 1;
    const int cb = (tid & 1) * 64;
    #pragma unroll
    for (int k = 0; k < 8; ++k) {
      u16x8 v = *(const u16x8*)&smem[row * 136 + cb + k * 8];
      *(u16x8*)&C[(long long)(tile_m + row) * ldc + tile_n + cb + k * 8] = v;
    }
  } else {
    #pragma unroll
    for (int p = 0; p < 2; ++p) {
      if ((wm >> 7) == p) {
        const int lwm = wm & 127;
        #pragma unroll
        for (int i = 0; i < 4; ++i) {
          const int lrow0 = lwm + i * 16 + lq * 4;
          #pragma unroll
          for (int j = 0; j < 4; ++j) {
            const int lcol = wn + j * 16 + lr;
            const float bcol = ((MODE == 1 || MODE == 3) && bias) ? bias[tile_n + lcol] : 0.f;
            #pragma unroll
            for (int r = 0; r < 4; ++r) {
              const float v = (MODE == 2) ? acc[i][j][r] : acc[i][j][r] * scale + bcol;
              smem[(lrow0 + r) * 136 + lcol] = f2bf(v);
            }
          }
        }
      }
      __syncthreads();
      if ((tid >> 8) == p) {
        const int t2 = tid & 255;
        const int row = t2 >> 1;
        const int cb = (t2 & 1) * 64;
        #pragma unroll
        for (int k = 0; k < 8; ++k) {
          u16x8 v = *(const u16x8*)&smem[row * 136 + cb + k * 8];
          *(u16x8*)&C[(long long)(tile_m + p * 128 + row) * ldc + tile_n + cb + k * 8] = v;
        }
      }
      if (p == 0) __syncthreads();
    }
  }
}

// prep: merged weight-convert + bias_pp + x transpose.
// blocks 0..1023:    wq,wk -> W3 rows 0..1023; wv -> wvT_b TRANSPOSED;
//                    wo -> wo_b; bqk=[bq|bk]; zero rowsum[8192].
// blocks 1024..1151: bpp[d] = sum_c wo[d,c]*bv[c] + bo[d] (one wave per d).
// blocks 1152+:      x fp32 [C][N] -> xT bf16 [N][C] (32x32 tiles).
__global__ __launch_bounds__(256) void prep(
    const float* __restrict__ x,
    const float* __restrict__ wq, const float* __restrict__ wk,
    const float* __restrict__ wv, const float* __restrict__ wo,
    const float* __restrict__ bq, const float* __restrict__ bk,
    const float* __restrict__ bv, const float* __restrict__ bo,
    unsigned short* __restrict__ W3, unsigned short* __restrict__ wvT_b,
    unsigned short* __restrict__ wo_b, unsigned short* __restrict__ xT,
    float* __restrict__ bqk, float* __restrict__ bpp,
    float* __restrict__ rowsum)
{
  __shared__ float tile[32][33];
  const int lin = blockIdx.x;
  const int tid = threadIdx.x;
  if (lin < 1024) {
    const int i = lin * 256 + tid;
    W3[i]          = f2bf(wq[i]);
    W3[262144 + i] = f2bf(wk[i]);
    wvT_b[i]       = f2bf(wv[(i & 511) * 512 + (i >> 9)]);  // wvT[c,t]=wv[t,c]
    wo_b[i]        = f2bf(wo[i]);
    if (i < 512) { bqk[i] = bq[i]; bqk[512 + i] = bk[i]; }
    if (i < 8192) rowsum[i] = 0.f;
  } else if (lin < 1152) {
    const int w = tid >> 6, lane = tid & 63;
    const int d = (lin - 1024) * 4 + w;
    const float* row = wo + (long long)d * 512;
    float s = 0.f;
    #pragma unroll
    for (int c = 0; c < 512; c += 64) s += row[c + lane] * bv[c + lane];
    #pragma unroll
    for (int o = 32; o > 0; o >>= 1) s += __shfl_xor(s, o, 64);
    if (lane == 0) bpp[d] = s + bo[d];
  } else {
    const int t = lin - 1152;
    const int n0 = (t & 127) * 32;
    const int c0 = ((t >> 7) & 15) * 32;
    const int bz = t >> 11;
    const int tx = tid & 31, ty = tid >> 5;
    const long long boff = (long long)bz * (512LL * 4096);
    #pragma unroll
    for (int k = 0; k < 32; k += 8)
      tile[ty + k][tx] = x[boff + (long long)(c0 + ty + k) * 4096 + n0 + tx];
    __syncthreads();
    #pragma unroll
    for (int k = 0; k < 32; k += 8)
      xT[boff + (long long)(n0 + ty + k) * 512 + c0 + tx] = f2bf(tile[tx][ty + k]);
  }
}

// out[b][d][n] = (sum of 4 bf16 partial streams)[b][d][n] / rowsum[b][n] + bpp[d]
// i = ((b*512 + d)*4096 + n); 8 contiguous n per thread; fp32 out
__global__ __launch_bounds__(256) void reduce4_norm_out(
    const unsigned short* __restrict__ p, long long L,
    const float* __restrict__ rowsum, const float* __restrict__ bpp,
    float* __restrict__ o)
{
  const long long i = 8LL * (blockIdx.x * 256 + threadIdx.x);
  const int b = (int)(i >> 21);
  const int d = (int)((i >> 12) & 511);
  const int n = (int)(i & 4095);
  const float bb = bpp[d];
  const float* rs = &rowsum[b * 4096 + n];
  u16x8 a  = *(const u16x8*)&p[i];
  u16x8 b1 = *(const u16x8*)&p[L + i];
  u16x8 c  = *(const u16x8*)&p[2 * L + i];
  u16x8 d1 = *(const u16x8*)&p[3 * L + i];
  f32x4 o0, o1;
  #pragma unroll
  for (int j = 0; j < 4; ++j) {
    o0[j] = ((bf2f(a[j]) + bf2f(b1[j])) + (bf2f(c[j]) + bf2f(d1[j]))) / rs[j] + bb;
    o1[j] = ((bf2f(a[4 + j]) + bf2f(b1[4 + j])) + (bf2f(c[4 + j]) + bf2f(d1[4 + j]))) / rs[4 + j] + bb;
  }
  *(f32x4*)&o[i] = o0;
  *(f32x4*)&o[i + 4] = o1;
}

extern "C" void kernel_launch(void* const* d_in, const int* in_sizes, int n_in,
                              void* d_out, int out_size, void* d_ws, size_t ws_size,
                              hipStream_t stream) {
  (void)in_sizes; (void)n_in; (void)out_size; (void)ws_size;
  const float* x  = (const float*)d_in[0];
  const float* wq = (const float*)d_in[1];
  const float* bq = (const float*)d_in[2];
  const float* wk = (const float*)d_in[3];
  const float* bk = (const float*)d_in[4];
  const float* wv = (const float*)d_in[5];
  const float* bv = (const float*)d_in[6];
  const float* wo = (const float*)d_in[7];
  const float* bo = (const float*)d_in[8];
  float* out = (float*)d_out;

  const int Cc = 512, N = 4096, Bn = 2;
  const int CC = Cc * Cc;                    // 262,144
  const long long NC  = (long long)N * Cc;   // 2,097,152

  // padded leading dims (non-power-of-2, multiples of 64) [R13 stride rule]
  const int LQK = 1088;                      // qkT ld
  const int LVO = 4224;                      // vo ld
  const int LS  = 4224;                      // S ld
  const long long sQK = (long long)N * LQK;  // 4,456,448
  const long long sVO = (long long)Cc * LVO; // 2,162,688
  const long long sS  = (long long)N * LS;   // 17,301,504

  char* wsb = (char*)d_ws;
  unsigned short* W3    = (unsigned short*)wsb;               // [1536][512] Wq|Wk|Wp
  unsigned short* wvT_b = W3 + 3LL * CC;                      // [512][512] wv^T
  unsigned short* wo_b  = wvT_b + CC;                         // [512][512]
  float*          bqk   = (float*)(wo_b + CC);                // [1024]
  float*          bpp   = bqk + 1024;                         // [512]  wo*bv+bo
  float*          rsum  = bpp + 512;                          // [8192]
  unsigned short* xT    = (unsigned short*)(rsum + 8192);     // [B][N][512]
  unsigned short* qkT   = xT + Bn * NC;                       // [B][N][1088] q|k
  unsigned short* vo    = qkT + Bn * sQK;                     // [B][512][4224]
  unsigned short* S     = vo + Bn * sVO;                      // [B][N][4224] P_unnorm
  unsigned short* part  = S + Bn * sS;                        // [4][B][512][4096] bf16

  const float inv_sqrt_c = 0.044194173824159216f;  // 1/sqrt(512)

  // D1: weights->bf16 (+wv^T), bqk, bpp, rowsum=0, x->xT   (merged)
  prep<<<dim3(1152 + 128 * 16 * Bn), 256, 0, stream>>>(
      x, wq, wk, wv, wo, bq, bk, bv, bo, W3, wvT_b, wo_b, xT, bqk, bpp, rsum);
  // D2: W3 rows 1024+: Wp[d,c] = sum_t wo[d,t] wv[t,c]
  gemm_abt<1, 128, 0><<<dim3(4, 4, 1), 256, 0, stream>>>(
      wo_b, 512, wvT_b, 512, W3 + 2LL * CC, 512, nullptr, nullptr,
      512, 512, 512, 1, 0, 0, 0, 0, 1.0f, nullptr, 0, 0);
  // D3: fused projections: d<1024 -> qkT[n,d]+bias (ld 1088); d>=1024 ->
  //     vo[d-1024][n] (transposed epilogue store, ld 4224)
  gemm_abt<3, 256, 0><<<dim3(12, N / 256, Bn), 512, 0, stream>>>(
      xT, Cc, W3, Cc, qkT, LQK, bqk, nullptr, N, 1536, Cc, 1,
      NC, 0, sQK, 0, 1.0f, vo, LVO, sVO);
  // D4: P_unnorm[n,m] = exp((1/sqrt(C)) sum_c q[n,c] k[m,c]); rsum += row sums
  gemm_abt<2, 256, 4><<<dim3(N / 128, N / 256, Bn), 512, 0, stream>>>(
      qkT, LQK, qkT + 512, LQK, S, LS, nullptr, rsum, N, N, Cc, 1,
      sQK, sQK, sS, 0, inv_sqrt_c, nullptr, 0, 0);
  // D5: part[ks][b][d][n] = sum_{m in split ks} vo[d,m] P_unnorm[n,m]
  gemm_abt<1, 256, 1><<<dim3(N / 128, 512 / 256, Bn * 4), 512, 0, stream>>>(
      vo, LVO, S, LS, part, N, nullptr, nullptr, 512, N, N, 4,
      sVO, sS, NC, (long long)Bn * NC, 1.0f, nullptr, 0, 0);
  // D6: out = (sum of partials)/l[n] + bpp[d]   (fp32, [B][C][H][W])
  reduce4_norm_out<<<dim3((int)((Bn * NC) / 2048)), 256, 0, stream>>>(
      part, (long long)Bn * NC, rsum, bpp, out);
}

// Round 15
// 239.792 us; speedup vs baseline: 1.0611x; 1.0375x over previous
//
#include <hip/hip_runtime.h>
#include <stdint.h>

typedef short s16x8 __attribute__((ext_vector_type(8)));
typedef unsigned short u16x8 __attribute__((ext_vector_type(8)));
typedef float f32x4 __attribute__((ext_vector_type(4)));

__device__ __forceinline__ float bf2f(unsigned short u) {
  union { unsigned u; float f; } c; c.u = ((unsigned)u) << 16; return c.f;
}
__device__ __forceinline__ unsigned short f2bf(float f) {
  union { float f; unsigned u; } c; c.f = f;
  unsigned u = c.u + 0x7fffu + ((c.u >> 16) & 1u);
  return (unsigned short)(u >> 16);
}

// async global->LDS, 16B per lane; lds base must be wave-uniform (HW adds lane*16)
__device__ __forceinline__ void g2l16(const void* g, void* l) {
  __builtin_amdgcn_global_load_lds(
      (const __attribute__((address_space(1))) void*)(unsigned long long)g,
      (__attribute__((address_space(3))) void*)(unsigned)(unsigned long long)l,
      16, 0, 0);
}

// C[M,N] = scale*(A[M,K] @ Bt[N,K]^T)(+bias). A,Bt bf16 K-contiguous.
// MT x 128 tile; MT=128: 4 waves / MT=256: 8 waves; wave tile always 64x64
// (4x4 16x16x32 MFMA). LDS staging XOR-swizzled (chunk c of row r at slot
// c^(r&7)): conflict-free [R6: SQ_LDS_BANK_CONFLICT=0].
// YB: XCD-locality remap (blocks sharing a B-tile sit 8 apart).
// STRIDE RULE [R13/R14 A/B]: input leading dims must NOT be powers of 2 —
// pow-2 row strides alias HBM banks/L2 sets and cost 10-14% on the dispatch.
// MODE 1: bf16 out, optional per-col bias (bias[N]), LDS-bounce vector store.
// MODE 2: bf16 out = exp(scale*acc), row sums atomically added to rowsum[bz*M+row].
// grid.z = batches*nsplit; ks=z%nsplit selects K-chunk, out += ks*sSplit.
// smem must cover BOTH staging ((MT+128)*64) and bounce (128*136) [R10 bug].
template <int MODE, int MT, int YB>
__global__ __launch_bounds__(2 * MT) void gemm_abt(
    const unsigned short* __restrict__ A, int lda,
    const unsigned short* __restrict__ Bt, int ldb,
    unsigned short* __restrict__ C, int ldc,
    const float* __restrict__ bias,
    float* __restrict__ rowsum,
    int M, int N, int K, int nsplit,
    long long sA, long long sBt, long long sC, long long sSplit,
    float scale)
{
  constexpr int STAGE_ELEMS  = (MT + 128) * 64;
  constexpr int BOUNCE_ELEMS = 128 * 136;
  constexpr int SMEM_ELEMS = STAGE_ELEMS > BOUNCE_ELEMS ? STAGE_ELEMS : BOUNCE_ELEMS;
  __shared__ __align__(16) unsigned short smem[SMEM_ELEMS];
  unsigned short* As = smem;
  unsigned short* Bs = smem + MT * 64;

  const int ks = blockIdx.z % nsplit;
  const int bz = blockIdx.z / nsplit;
  A  += (long long)bz * sA;
  Bt += (long long)bz * sBt;
  C  += (long long)bz * sC + (long long)ks * sSplit;

  int bx, by;
  if (YB > 0) {
    const int lin = blockIdx.x + (int)gridDim.x * blockIdx.y;
    bx = (lin & 7) | ((lin >> (3 + YB)) << 3);
    by = (lin >> 3) & ((1 << YB) - 1);
  } else {
    bx = blockIdx.x;
    by = blockIdx.y;
  }

  const int tile_m = by * MT;
  const int tile_n = bx * 128;

  const int tid  = threadIdx.x;
  const int wid  = tid >> 6;
  const int lane = tid & 63;
  const int wm = (wid >> 1) * 64;   // wave's 64-row strip (2 or 4 strips)
  const int wn = (wid & 1) * 64;    // wave's 64-col strip
  const int lr = lane & 15;         // fragment row (m for A, n for B)
  const int lq = lane >> 4;         // quad -> k offset lq*8

  const int srow = lane >> 3;                         // row within 8-row chunk
  const int scol = ((lane & 7) ^ (srow & 7)) * 8;     // XOR-swizzled col chunk

  f32x4 acc[4][4];
  const f32x4 zero4 = {0.f, 0.f, 0.f, 0.f};
  #pragma unroll
  for (int i = 0; i < 4; ++i)
    #pragma unroll
    for (int j = 0; j < 4; ++j) acc[i][j] = zero4;

  const unsigned short* Arow = A  + (long long)tile_m * lda;
  const unsigned short* Brow = Bt + (long long)tile_n * ldb;

  const int kLen = K / nsplit;
  const int kBeg = ks * kLen;

  constexpr int ACH   = MT / 8;          // A chunks (8 rows x 64 cols = 1KB)
  constexpr int NCH   = ACH + 16;        // + 16 B chunks
  constexpr int NW    = MT / 32;         // waves
  constexpr int PERW  = NCH / NW;        // chunks per wave (8 or 6)

  for (int k0 = kBeg; k0 < kBeg + kLen; k0 += 64) {
    #pragma unroll
    for (int c = 0; c < PERW; ++c) {
      const int chunk = wid * PERW + c;  // wave-uniform
      if (chunk < ACH) {
        const int row = chunk * 8 + srow;
        g2l16(Arow + (long long)row * lda + k0 + scol, smem + chunk * 512);
      } else {
        const int row = (chunk - ACH) * 8 + srow;
        g2l16(Brow + (long long)row * ldb + k0 + scol, smem + chunk * 512);
      }
    }
    __syncthreads();
    #pragma unroll
    for (int kss = 0; kss < 2; ++kss) {
      const int cch = kss * 4 + lq;                 // 16B-chunk index in row
      s16x8 af[4], bfr[4];
      #pragma unroll
      for (int i = 0; i < 4; ++i) {
        const int row = wm + i * 16 + lr;
        af[i] = *(const s16x8*)&As[row * 64 + ((cch ^ (row & 7)) * 8)];
      }
      #pragma unroll
      for (int j = 0; j < 4; ++j) {
        const int row = wn + j * 16 + lr;
        bfr[j] = *(const s16x8*)&Bs[row * 64 + ((cch ^ (row & 7)) * 8)];
      }
      #pragma unroll
      for (int i = 0; i < 4; ++i)
        #pragma unroll
        for (int j = 0; j < 4; ++j)
          acc[i][j] = __builtin_amdgcn_mfma_f32_16x16x32_bf16(af[i], bfr[j], acc[i][j], 0, 0, 0);
    }
    __syncthreads();
  }

  // ---- epilogue. C/D layout col=lane&15, row=(lane>>4)*4+reg [m89-verified]
  // MODE 2: exp-transform acc in regs + rowsum atomics (no LDS dependency)
  if (MODE == 2) {
    #pragma unroll
    for (int i = 0; i < 4; ++i) {
      float rs[4] = {0.f, 0.f, 0.f, 0.f};
      #pragma unroll
      for (int j = 0; j < 4; ++j)
        #pragma unroll
        for (int r = 0; r < 4; ++r) {
          acc[i][j][r] = __expf(acc[i][j][r] * scale);
          rs[r] += acc[i][j][r];
        }
      #pragma unroll
      for (int r = 0; r < 4; ++r) {
        float s = rs[r];
        s += __shfl_xor(s, 1); s += __shfl_xor(s, 2);
        s += __shfl_xor(s, 4); s += __shfl_xor(s, 8);
        if (lr == 0)
          atomicAdd(&rowsum[(long long)bz * M + tile_m + wm + i * 16 + lq * 4 + r], s);
      }
    }
  }

  // bounce passes: 128 rows at a time through smem (ld=136)
  if (MT == 128) {
    #pragma unroll
    for (int i = 0; i < 4; ++i) {
      const int lrow0 = wm + i * 16 + lq * 4;
      #pragma unroll
      for (int j = 0; j < 4; ++j) {
        const int lcol = wn + j * 16 + lr;
        const float bcol = (MODE == 1 && bias) ? bias[tile_n + lcol] : 0.f;
        #pragma unroll
        for (int r = 0; r < 4; ++r) {
          const float v = (MODE == 2) ? acc[i][j][r] : acc[i][j][r] * scale + bcol;
          smem[(lrow0 + r) * 136 + lcol] = f2bf(v);
        }
      }
    }
    __syncthreads();
    const int row = tid >> 1;
    const int cb = (tid & 1) * 64;
    #pragma unroll
    for (int k = 0; k < 8; ++k) {
      u16x8 v = *(const u16x8*)&smem[row * 136 + cb + k * 8];
      *(u16x8*)&C[(long long)(tile_m + row) * ldc + tile_n + cb + k * 8] = v;
    }
  } else {
    #pragma unroll
    for (int p = 0; p < 2; ++p) {
      if ((wm >> 7) == p) {
        const int lwm = wm & 127;
        #pragma unroll
        for (int i = 0; i < 4; ++i) {
          const int lrow0 = lwm + i * 16 + lq * 4;
          #pragma unroll
          for (int j = 0; j < 4; ++j) {
            const int lcol = wn + j * 16 + lr;
            const float bcol = (MODE == 1 && bias) ? bias[tile_n + lcol] : 0.f;
            #pragma unroll
            for (int r = 0; r < 4; ++r) {
              const float v = (MODE == 2) ? acc[i][j][r] : acc[i][j][r] * scale + bcol;
              smem[(lrow0 + r) * 136 + lcol] = f2bf(v);
            }
          }
        }
      }
      __syncthreads();
      if ((tid >> 8) == p) {
        const int t2 = tid & 255;
        const int row = t2 >> 1;
        const int cb = (t2 & 1) * 64;
        #pragma unroll
        for (int k = 0; k < 8; ++k) {
          u16x8 v = *(const u16x8*)&smem[row * 136 + cb + k * 8];
          *(u16x8*)&C[(long long)(tile_m + p * 128 + row) * ldc + tile_n + cb + k * 8] = v;
        }
      }
      if (p == 0) __syncthreads();
    }
  }
}

// blocks 0..1023: wq,wk -> W3 rows 0..1023; wv -> wvT_b TRANSPOSED; wo -> wo_b;
// bqk3 = [bq | bk | 0]; zero rowsum [8192].
// blocks 1024..1151: bpp[d] = sum_c wo[d,c]*bv[c] + bo[d] (one wave per d).
__global__ __launch_bounds__(256) void cvt_weights(
    const float* __restrict__ wq, const float* __restrict__ wk,
    const float* __restrict__ wv, const float* __restrict__ wo,
    const float* __restrict__ bq, const float* __restrict__ bk,
    const float* __restrict__ bv, const float* __restrict__ bo,
    unsigned short* __restrict__ W3, unsigned short* __restrict__ wvT_b,
    unsigned short* __restrict__ wo_b, float* __restrict__ bqk3,
    float* __restrict__ bpp, float* __restrict__ rowsum, int n)
{
  if ((int)blockIdx.x < 1024) {
    const int i = blockIdx.x * 256 + threadIdx.x;
    if (i < n) {
      W3[i]      = f2bf(wq[i]);
      W3[n + i]  = f2bf(wk[i]);
      wvT_b[i]   = f2bf(wv[(i & 511) * 512 + (i >> 9)]);  // wvT[c,t]=wv[t,c]
      wo_b[i]    = f2bf(wo[i]);
    }
    if (i < 512) {
      bqk3[i]        = bq[i];
      bqk3[512 + i]  = bk[i];
      bqk3[1024 + i] = 0.f;
    }
    if (i < 8192) rowsum[i] = 0.f;
  } else {
    const int w = threadIdx.x >> 6, lane = threadIdx.x & 63;
    const int d = (blockIdx.x - 1024) * 4 + w;
    const float* row = wo + (long long)d * 512;
    float s = 0.f;
    #pragma unroll
    for (int c = 0; c < 512; c += 64) s += row[c + lane] * bv[c + lane];
    #pragma unroll
    for (int o = 32; o > 0; o >>= 1) s += __shfl_xor(s, o, 64);
    if (lane == 0) bpp[d] = s + bo[d];
  }
}

// x fp32 [C][N] -> xT bf16 [N][C], per-batch via grid.z. block (32,8).
__global__ __launch_bounds__(256) void transpose_cn(
    const float* __restrict__ x, unsigned short* __restrict__ xT,
    int C, int N)
{
  __shared__ float tile[32][33];
  const long long boff = (long long)blockIdx.z * C * N;
  const int n0 = blockIdx.x * 32;
  const int c0 = blockIdx.y * 32;
  const int tx = threadIdx.x;
  const int ty = threadIdx.y;
  #pragma unroll
  for (int k = 0; k < 32; k += 8)
    tile[ty + k][tx] = x[boff + (long long)(c0 + ty + k) * N + n0 + tx];
  __syncthreads();
  #pragma unroll
  for (int k = 0; k < 32; k += 8)
    xT[boff + (long long)(n0 + ty + k) * C + c0 + tx] = f2bf(tile[tx][ty + k]);
}

// bf16 transpose: dst[c][r] = src[r][c]
__global__ __launch_bounds__(256) void transpose_bf(
    const unsigned short* __restrict__ src, int srcLd, long long sSrc,
    unsigned short* __restrict__ dst, int dstLd, long long sDst,
    int R, int Cc)
{
  __shared__ unsigned short tile[32][33];
  const int r0 = blockIdx.x * 32;
  const int c0 = blockIdx.y * 32;
  const int tx = threadIdx.x;
  const int ty = threadIdx.y;
  const long long so = (long long)blockIdx.z * sSrc;
  const long long dofs = (long long)blockIdx.z * sDst;
  #pragma unroll
  for (int k = 0; k < 32; k += 8)
    tile[ty + k][tx] = src[so + (long long)(r0 + ty + k) * srcLd + c0 + tx];
  __syncthreads();
  #pragma unroll
  for (int k = 0; k < 32; k += 8)
    dst[dofs + (long long)(c0 + ty + k) * dstLd + r0 + tx] = tile[tx][ty + k];
}

// out[b][d][n] = (sum of 4 bf16 partial streams)[b][d][n] / rowsum[b][n] + bpp[d]
// i = ((b*512 + d)*4096 + n); 8 contiguous n per thread; fp32 out
__global__ __launch_bounds__(256) void reduce4_norm_out(
    const unsigned short* __restrict__ p, long long L,
    const float* __restrict__ rowsum, const float* __restrict__ bpp,
    float* __restrict__ o)
{
  const long long i = 8LL * (blockIdx.x * 256 + threadIdx.x);
  const int b = (int)(i >> 21);
  const int d = (int)((i >> 12) & 511);
  const int n = (int)(i & 4095);
  const float bb = bpp[d];
  const float* rs = &rowsum[b * 4096 + n];
  u16x8 a  = *(const u16x8*)&p[i];
  u16x8 b1 = *(const u16x8*)&p[L + i];
  u16x8 c  = *(const u16x8*)&p[2 * L + i];
  u16x8 d1 = *(const u16x8*)&p[3 * L + i];
  f32x4 o0, o1;
  #pragma unroll
  for (int j = 0; j < 4; ++j) {
    o0[j] = ((bf2f(a[j]) + bf2f(b1[j])) + (bf2f(c[j]) + bf2f(d1[j]))) / rs[j] + bb;
    o1[j] = ((bf2f(a[4 + j]) + bf2f(b1[4 + j])) + (bf2f(c[4 + j]) + bf2f(d1[4 + j]))) / rs[4 + j] + bb;
  }
  *(f32x4*)&o[i] = o0;
  *(f32x4*)&o[i + 4] = o1;
}

extern "C" void kernel_launch(void* const* d_in, const int* in_sizes, int n_in,
                              void* d_out, int out_size, void* d_ws, size_t ws_size,
                              hipStream_t stream) {
  (void)in_sizes; (void)n_in; (void)out_size; (void)ws_size;
  const float* x  = (const float*)d_in[0];
  const float* wq = (const float*)d_in[1];
  const float* bq = (const float*)d_in[2];
  const float* wk = (const float*)d_in[3];
  const float* bk = (const float*)d_in[4];
  const float* wv = (const float*)d_in[5];
  const float* bv = (const float*)d_in[6];
  const float* wo = (const float*)d_in[7];
  const float* bo = (const float*)d_in[8];
  float* out = (float*)d_out;

  const int Cc = 512, N = 4096, Bn = 2, C3 = 1536;
  const int CC = Cc * Cc;                    // 262,144
  const long long NC  = (long long)N * Cc;   // 2,097,152
  const long long NC3 = (long long)N * C3;   // 6,291,456

  // padded leading dims for PV inputs (non-pow-2, mult of 64) [R13/R14 rule]
  const int LVO = 4224;                      // vo ld
  const int LS  = 4224;                      // S ld
  const long long sVO = (long long)Cc * LVO; // 2,162,688
  const long long sS  = (long long)N * LS;   // 17,301,504

  char* wsb = (char*)d_ws;
  unsigned short* W3    = (unsigned short*)wsb;               // [1536][512] Wq|Wk|Wp
  unsigned short* wvT_b = W3 + 3LL * CC;                      // [512][512] wv^T
  unsigned short* wo_b  = wvT_b + CC;                         // [512][512]
  float*          bqk3  = (float*)(wo_b + CC);                // [1536]
  float*          bpp   = bqk3 + 1536;                        // [512]  wo*bv+bo
  float*          rsum  = bpp + 512;                          // [8192]
  unsigned short* xT    = (unsigned short*)(rsum + 8192);     // [B][N][512]
  unsigned short* qkvoT = xT + Bn * NC;                       // [B][N][1536] q|k|voT
  unsigned short* vo    = qkvoT + Bn * NC3;                   // [B][512][4224]
  unsigned short* S     = vo + Bn * sVO;                      // [B][N][4224] P_unnorm
  unsigned short* part  = S + Bn * sS;                        // [4][B][512][4096] bf16

  const float inv_sqrt_c = 0.044194173824159216f;  // 1/sqrt(512)

  cvt_weights<<<dim3(1152), 256, 0, stream>>>(
      wq, wk, wv, wo, bq, bk, bv, bo, W3, wvT_b, wo_b, bqk3, bpp, rsum, CC);
  // W3 rows 1024+: Wp[d,c] = sum_t wo[d,t] wv[t,c]
  gemm_abt<1, 128, 0><<<dim3(4, 4, 1), 256, 0, stream>>>(
      wo_b, 512, wvT_b, 512, W3 + 2LL * CC, 512, nullptr, nullptr,
      512, 512, 512, 1, 0, 0, 0, 0, 1.0f);
  transpose_cn<<<dim3(N / 32, Cc / 32, Bn), dim3(32, 8), 0, stream>>>(x, xT, Cc, N);

  // qkvoT[n,d] = sum_c xT[n,c] W3[d,c] + bqk3[d]   (d 0..1535: q|k|voT)
  gemm_abt<1, 256, 0><<<dim3(C3 / 128, N / 256, Bn), 512, 0, stream>>>(
      xT, Cc, W3, Cc, qkvoT, C3, bqk3, nullptr, N, C3, Cc, 1,
      NC, 0, NC3, 0, 1.0f);
  // vo[d,n] = qkvoT[n, 1024+d]   (dst padded ld 4224)
  transpose_bf<<<dim3(N / 32, Cc / 32, Bn), dim3(32, 8), 0, stream>>>(
      qkvoT + 1024, C3, NC3, vo, LVO, sVO, N, Cc);
  // P_unnorm[n,m] = exp((1/sqrt(C)) sum_c q[n,c] k[m,c]); rsum += row sums
  // YB=4: 16 y-blocks sharing each kT B-tile grouped 8-apart (same XCD)
  gemm_abt<2, 256, 4><<<dim3(N / 128, N / 256, Bn), 512, 0, stream>>>(
      qkvoT, C3, qkvoT + 512, C3, S, LS, nullptr, rsum, N, N, Cc, 1,
      NC3, NC3, sS, 0, inv_sqrt_c);
  // part[ks][b][d][n] = sum_{m in split ks} vo[d,m] P_unnorm[n,m]
  // YB=1; A=vo ld 4224, B=S ld 4224 (de-aliased PV inputs — the R15 delta)
  gemm_abt<1, 256, 1><<<dim3(N / 128, 512 / 256, Bn * 4), 512, 0, stream>>>(
      vo, LVO, S, LS, part, N, nullptr, nullptr, 512, N, N, 4,
      sVO, sS, NC, (long long)Bn * NC, 1.0f);
  // out = (sum of partials)/l[n] + bpp[d]   (fp32, [B][C][H][W])
  reduce4_norm_out<<<dim3((int)((Bn * NC) / 2048)), 256, 0, stream>>>(
      part, (long long)Bn * NC, rsum, bpp, out);
}